// Round 7
// baseline (199.275 us; speedup 1.0000x reference)
//
#include <hip/hip_runtime.h>
#include <math.h>

#define B_  8
#define S_  8192
#define D_  64
#define H_  8
#define NB_ 128
#define NC_ 1024
#define REP_CAP 65536
#define T2_ 2e-3f   // repair margin >= 10x the split-f16 worst-case error (~1.5e-4)

typedef _Float16 f16x8 __attribute__((ext_vector_type(8)));
typedef _Float16 f16x2 __attribute__((ext_vector_type(2)));
typedef float    f32x4 __attribute__((ext_vector_type(4)));
typedef unsigned int uint_;

#define MFMA16(A, Bv, C) __builtin_amdgcn_mfma_f32_16x16x32_f16(A, Bv, C, 0, 0, 0)

// ---------------------------------------------------------------------------
// Kernel 0: rot prep — transpose+split rot into [h][i][f] f16 hi/lo, PLUS
// fp32 rotT [h][i][f] (contiguous per-lane rows for repair); zero cnt.
// ---------------------------------------------------------------------------
__global__ __launch_bounds__(256) void rot_prep_kernel(
    const float* __restrict__ rot, _Float16* __restrict__ rotHi,
    _Float16* __restrict__ rotLo, float* __restrict__ rotT,
    int* __restrict__ cnt)
{
  __shared__ float rs[64 * 64];               // [f][i]
  const int tid = threadIdx.x, h = blockIdx.x;
  if (h == 0 && tid == 0) *cnt = 0;
#pragma unroll
  for (int it = 0; it < 16; ++it) {
    const int f = it * 4 + (tid >> 6), i = tid & 63;
    rs[f * 64 + i] = rot[f * 512 + h * 64 + i];
  }
  __syncthreads();
  const int i = tid & 63, grp = tid >> 6;
  _Float16 hi[16], lo[16];
  float tf[16];
#pragma unroll
  for (int ff = 0; ff < 16; ++ff) {
    const float x = rs[(grp * 16 + ff) * 64 + i];
    tf[ff] = x;
    hi[ff] = (_Float16)x;
    lo[ff] = (_Float16)(x - (float)hi[ff]);
  }
  f16x8* dH = (f16x8*)(rotHi + h * 4096 + i * 64 + grp * 16);
  f16x8* dL = (f16x8*)(rotLo + h * 4096 + i * 64 + grp * 16);
  dH[0] = ((f16x8*)hi)[0]; dH[1] = ((f16x8*)hi)[1];
  dL[0] = ((f16x8*)lo)[0]; dL[1] = ((f16x8*)lo)[1];
  float4* dT = (float4*)(rotT + h * 4096 + i * 64 + grp * 16);
#pragma unroll
  for (int k = 0; k < 4; ++k) dT[k] = ((float4*)tf)[k];
}

// ---------------------------------------------------------------------------
// Kernel 1 (FUSED): token prep (q16/kn16/v16) + hash, one 64-token tile per
// block. b = blockIdx&7 (XCD-batch swizzle). rot slices for h+1 are
// register-prefetched before h's ds_writes (latency hidden under MFMA).
// ---------------------------------------------------------------------------
__global__ __launch_bounds__(256) void hash_kernel(
    const float* __restrict__ qk, const float* __restrict__ v,
    const _Float16* __restrict__ rotHi, const _Float16* __restrict__ rotLo,
    _Float16* __restrict__ q16, _Float16* __restrict__ kn16,
    _Float16* __restrict__ v16,
    int* __restrict__ bucket, int* __restrict__ cnt, int2* __restrict__ list)
{
  __shared__ _Float16 rH[64 * 72];            // 9216 B
  __shared__ _Float16 rL[64 * 72];            // 9216 B
  const int tid  = threadIdx.x;
  const int b    = blockIdx.x & 7;            // XCD-batch swizzle
  const int tile = blockIdx.x >> 3;           // 128 tiles x 64 tokens
  const int lane = tid & 63, w = tid >> 6;
  const int m16  = lane & 15, qd = lane >> 4;

  // ---- prep-token part: thread (r, qu) owns quarter-row of token r ----
  {
    const int gt = b * S_ + tile * 64 + (tid >> 2);
    const int qu = tid & 3;
    const size_t off = (size_t)gt * 64 + qu * 16;
    float x[16];
#pragma unroll
    for (int k = 0; k < 4; ++k) ((float4*)x)[k] = ((const float4*)(qk + off))[k];
    float ss = 0.f;
#pragma unroll
    for (int k = 0; k < 16; ++k) ss = fmaf(x[k], x[k], ss);
    ss += __shfl_xor(ss, 1); ss += __shfl_xor(ss, 2);
    const float inv = 0.125f / (sqrtf(ss) + 1e-6f);
    f16x8 qh[2], kn[2];
#pragma unroll
    for (int j = 0; j < 16; ++j) {
      qh[j >> 3][j & 7] = (_Float16)x[j];
      kn[j >> 3][j & 7] = (_Float16)(x[j] * inv);
    }
    ((f16x8*)(q16  + off))[0] = qh[0]; ((f16x8*)(q16  + off))[1] = qh[1];
    ((f16x8*)(kn16 + off))[0] = kn[0]; ((f16x8*)(kn16 + off))[1] = kn[1];
    float y[16];
#pragma unroll
    for (int k = 0; k < 4; ++k) ((float4*)y)[k] = ((const float4*)(v + off))[k];
    f16x8 vv[2];
#pragma unroll
    for (int j = 0; j < 16; ++j) vv[j >> 3][j & 7] = (_Float16)y[j];
    ((f16x8*)(v16 + off))[0] = vv[0]; ((f16x8*)(v16 + off))[1] = vv[1];
  }

  // ---- hash part: thread (w, m16, qd) owns token t, dims 8qd.. ----
  const int t = tile * 64 + w * 16 + m16;
  f16x8 BH0, BH1, BL0, BL1;                   // split-f16 B-fragments
  {
    const float* src = qk + ((size_t)b * S_ + t) * 64 + 8 * qd;
    float x[16];
    ((float4*)x)[0] = ((const float4*)src)[0];
    ((float4*)x)[1] = ((const float4*)(src + 4))[0];
    ((float4*)x)[2] = ((const float4*)(src + 32))[0];
    ((float4*)x)[3] = ((const float4*)(src + 36))[0];
#pragma unroll
    for (int j = 0; j < 8; ++j) {
      const _Float16 h0 = (_Float16)x[j];
      BH0[j] = h0; BL0[j] = (_Float16)(x[j] - (float)h0);
      const _Float16 h1 = (_Float16)x[j + 8];
      BH1[j] = h1; BL1[j] = (_Float16)(x[j + 8] - (float)h1);
    }
  }
  const int srow = tid >> 2, scol = (tid & 3) * 16;
  const uint_ qd16 = (uint_)(qd << 4);

  // prefetch h=0 rot slice into registers
  f16x8 cH0, cH1, cL0, cL1;
  {
    const _Float16* gH = rotHi + srow * 64 + scol;
    const _Float16* gL = rotLo + srow * 64 + scol;
    cH0 = ((const f16x8*)gH)[0]; cH1 = ((const f16x8*)gH)[1];
    cL0 = ((const f16x8*)gL)[0]; cL1 = ((const f16x8*)gL)[1];
  }

#pragma unroll 1
  for (int h = 0; h < 8; ++h) {
    __syncthreads();                          // prev iter's LDS reads done
    f16x8 nH0, nH1, nL0, nL1;
    if (h < 7) {                              // issue h+1 loads (overlap compute)
      const _Float16* gH = rotHi + (h + 1) * 4096 + srow * 64 + scol;
      const _Float16* gL = rotLo + (h + 1) * 4096 + srow * 64 + scol;
      nH0 = ((const f16x8*)gH)[0]; nH1 = ((const f16x8*)gH)[1];
      nL0 = ((const f16x8*)gL)[0]; nL1 = ((const f16x8*)gL)[1];
    }
    *(f16x8*)(rH + srow * 72 + scol)     = cH0;
    *(f16x8*)(rH + srow * 72 + scol + 8) = cH1;
    *(f16x8*)(rL + srow * 72 + scol)     = cL0;
    *(f16x8*)(rL + srow * 72 + scol + 8) = cL1;
    __syncthreads();

    f32x4 acc[4];
#pragma unroll
    for (int mt = 0; mt < 4; ++mt) acc[mt] = (f32x4){0.f, 0.f, 0.f, 0.f};
#pragma unroll
    for (int mt = 0; mt < 4; ++mt) {
      const _Float16* aH = rH + (16 * mt + m16) * 72 + 8 * qd;
      const _Float16* aL = rL + (16 * mt + m16) * 72 + 8 * qd;
      const f16x8 AH0 = *(const f16x8*)aH;
      const f16x8 AH1 = *(const f16x8*)(aH + 32);
      const f16x8 AL0 = *(const f16x8*)aL;
      const f16x8 AL1 = *(const f16x8*)(aL + 32);
      acc[mt] = MFMA16(AH0, BH0, acc[mt]);
      acc[mt] = MFMA16(AH1, BH1, acc[mt]);
      acc[mt] = MFMA16(AH0, BL0, acc[mt]);
      acc[mt] = MFMA16(AH1, BL1, acc[mt]);
      acc[mt] = MFMA16(AL0, BH0, acc[mt]);
      acc[mt] = MFMA16(AL1, BH1, acc[mt]);
    }

    float v1M = -1e30f, v2M = -1e30f, v1m = 1e30f, v2m = 1e30f;
#pragma unroll
    for (int mt = 0; mt < 4; ++mt)
#pragma unroll
      for (int rg = 0; rg < 4; ++rg) {
        uint_ u = __float_as_uint(acc[mt][rg]);
        u = (u & 0xFFFFFFC0u) | qd16 | (uint_)((mt << 2) | rg);
        const float xk = __uint_as_float(u);
        v2M = __builtin_amdgcn_fmed3f(v1M, v2M, xk);
        v1M = fmaxf(v1M, xk);
        v2m = __builtin_amdgcn_fmed3f(v1m, v2m, xk);
        v1m = fminf(v1m, xk);
      }
#pragma unroll
    for (int off = 16; off <= 32; off <<= 1) {
      const float o1M = __shfl_xor(v1M, off), o2M = __shfl_xor(v2M, off);
      v2M = __builtin_amdgcn_fmed3f(v1M, o1M, fmaxf(v2M, o2M));
      v1M = fmaxf(v1M, o1M);
      const float o1m = __shfl_xor(v1m, off), o2m = __shfl_xor(v2m, off);
      v2m = __builtin_amdgcn_fmed3f(v1m, o1m, fminf(v2m, o2m));
      v1m = fminf(v1m, o1m);
    }
    if (qd == 0) {
      const uint_ cM = __float_as_uint(v1M) & 63u;
      const uint_ cm = __float_as_uint(v1m) & 63u;
      const int ixM = 16 * (int)((cM >> 2) & 3u) + 4 * (int)(cM >> 4) + (int)(cM & 3u);
      const int ixm = 16 * (int)((cm >> 2) & 3u) + 4 * (int)(cm >> 4) + (int)(cm & 3u);
      const int bkt = (v1M >= -v1m) ? ixM : 64 + ixm;
      bucket[((size_t)(b * 8 + h)) * S_ + t] = bkt;
      const bool flag = ((v1M - v2M) < T2_) | ((v2m - v1m) < T2_) |
                        (fabsf(v1M + v1m) < T2_);
      if (flag) {
        const int s = atomicAdd(cnt, 1);
        if (s < REP_CAP) list[s] = make_int2(b * 8 + h, t);
      }
    }
    cH0 = nH0; cH1 = nH1; cL0 = nL0; cL1 = nL1;
  }
}

// ---------------------------------------------------------------------------
// Kernel 1b: exact fp64 repair for flagged tokens (rotT contiguous rows).
// ---------------------------------------------------------------------------
__global__ __launch_bounds__(256) void repair_kernel(
    const float* __restrict__ qk, const float* __restrict__ rotT,
    const int* __restrict__ cnt, const int2* __restrict__ list,
    int* __restrict__ bucket)
{
  const int n = min(*cnt, REP_CAP);
  const int lane = threadIdx.x & 63;
  const int wid  = (blockIdx.x * 256 + threadIdx.x) >> 6;
  const int nw   = gridDim.x * 4;
  for (int idx = wid; idx < n; idx += nw) {
    const int bh = list[idx].x, t = list[idx].y;
    const int b = bh >> 3, hh = bh & 7;
    const float* qrow = qk + ((size_t)b * S_ + t) * D_;
    const float* rcol = rotT + hh * 4096 + lane * 64;
    double acc = 0.0;
#pragma unroll
    for (int f0 = 0; f0 < 64; f0 += 4) {
      const float4 rq = *(const float4*)(qrow + f0);
      const float4 rc = *(const float4*)(rcol + f0);
      acc = fma((double)rq.x, (double)rc.x, acc);
      acc = fma((double)rq.y, (double)rc.y, acc);
      acc = fma((double)rq.z, (double)rc.z, acc);
      acc = fma((double)rq.w, (double)rc.w, acc);
    }
    double vM = acc; int iM = lane;
    double vm = acc; int im = lane;
#pragma unroll
    for (int off = 32; off >= 1; off >>= 1) {
      const double voM = __shfl_xor(vM, off); const int ioM = __shfl_xor(iM, off);
      if (voM > vM || (voM == vM && ioM < iM)) { vM = voM; iM = ioM; }
      const double vom = __shfl_xor(vm, off); const int iom = __shfl_xor(im, off);
      if (vom < vm || (vom == vm && iom < im)) { vm = vom; im = iom; }
    }
    if (lane == 0) {
      const int bkt = (vM >= -vm) ? iM : 64 + im;
      bucket[(size_t)bh * S_ + t] = bkt;
    }
  }
}

// ---------------------------------------------------------------------------
// Kernel 2: stable counting sort — ATOMIC-FREE (r5 version). One ballot pass
// computes (bucket, rank, leader counts); 2-wave scan; in-place counts->
// bases; scatter reuses saved ranks. Bit-identical output.
// ---------------------------------------------------------------------------
__global__ __launch_bounds__(1024) void sort_kernel(
    const int* __restrict__ bucket, int* __restrict__ st)
{
  __shared__ uint_ hist32[128 * 67];          // 34304 B; u16 view [bk][134]
  __shared__ unsigned short lb[S_];
  __shared__ int off[128];
  __shared__ int wtot;
  unsigned short* hist16 = (unsigned short*)hist32;
  const int tid = threadIdx.x;
  const int bh  = blockIdx.x;
  const size_t base = (size_t)bh * S_;
  const int lane = tid & 63;
  const unsigned long long ltmask = (1ull << lane) - 1ull;

#pragma unroll
  for (int k = 0; k < 9; ++k) {
    const int i = k * 1024 + tid;
    if (i < 128 * 67) hist32[i] = 0;
  }
  __syncthreads();

  // ---- single ballot pass: labels, ranks, leader counts ----
  int rl[8];
#pragma unroll
  for (int k = 0; k < 8; ++k) {
    const int t = k * 1024 + tid;
    const int bk = bucket[base + t];
    lb[t] = (unsigned short)bk;
    unsigned long long same = ~0ull;
#pragma unroll
    for (int bit = 0; bit < 7; ++bit) {
      const unsigned long long m = __ballot((bk >> bit) & 1);
      same &= ((bk >> bit) & 1) ? m : ~m;
    }
    rl[k] = __popcll(same & ltmask);
    if ((same & ltmask) == 0ull)              // leader of this bucket-set
      hist16[bk * 134 + (t >> 6)] = (unsigned short)__popcll(same);
  }
  __syncthreads();

  // ---- per-bucket totals + 2-wave exclusive scan over 128 buckets ----
  int s = 0;
  if (tid < 128) {
    const uint_* row = hist32 + tid * 67;
#pragma unroll
    for (int g2 = 0; g2 < 64; ++g2) {
      const uint_ wv = row[g2];
      s += (int)((wv & 0xFFFFu) + (wv >> 16));
    }
  }
  int x = s;
#pragma unroll
  for (int d = 1; d < 64; d <<= 1) {
    const int y = __shfl_up(x, d);
    if (lane >= d) x += y;
  }
  if (tid == 63) wtot = x;
  __syncthreads();
  if (tid < 128) {
    if (tid >= 64) x += wtot;
    off[tid] = x - s;                         // exclusive prefix
  }
  __syncthreads();

  // ---- counts -> group bases (in place) ----
  if (tid < 128) {
    int run = off[tid];
    unsigned short* rowp = hist16 + tid * 134;
#pragma unroll
    for (int g = 0; g < 128; ++g) {
      const int cg = rowp[g];
      rowp[g] = (unsigned short)run;
      run += cg;
    }
  }
  __syncthreads();

  // ---- scatter ----
  const int b = bh >> 3, h = bh & 7;
  const size_t stb = (size_t)b * (H_ * S_) + (size_t)h * S_;
#pragma unroll
  for (int k = 0; k < 8; ++k) {
    const int t = k * 1024 + tid;
    const int bk = (int)lb[t];
    const int gb = (int)hist16[bk * 134 + (t >> 6)];
    st[stb + gb + rl[k]] = t;
  }
}

// ---------------------------------------------------------------------------
// Kernel 3: bucketed attention — swapped QK^T, XCD-batch swizzle, setprio,
// LDS O-restage epilogue. NEW: so/slog stores are NON-TEMPORAL so the 8MB/XCD
// write stream doesn't evict the ~3.3MB gather working set from L2.
// ---------------------------------------------------------------------------
__global__ __launch_bounds__(256, 8) void attn_kernel(
    const _Float16* __restrict__ q16, const _Float16* __restrict__ kn16,
    const _Float16* __restrict__ v16, const int* __restrict__ st,
    _Float16* __restrict__ so, float* __restrict__ slog)
{
  __shared__ _Float16 smem[128 * 72];         // union: sK[128*72] | sV[64*136] | O[64*72]
  __shared__ __align__(16) int sIds[128];

  const int tid = threadIdx.x;
  const int b   = blockIdx.x & 7;             // XCD-batch swizzle
  const int c   = blockIdx.x >> 3;
  const int cm1 = (c + NC_ - 1) & (NC_ - 1);
  const size_t bst = (size_t)b * (H_ * S_);
  const size_t row0 = bst + (size_t)c * 64;
  const size_t row1 = bst + (size_t)cm1 * 64;

  const int lane = tid & 63;
  const int w    = tid >> 6;
  const int m16  = lane & 15;
  const int qd   = lane >> 4;

  if (tid < 128) sIds[tid] = (tid < 64) ? st[row0 + tid] : st[row1 + tid - 64];

  const int rid = st[row0 + 16 * w + m16];
  f16x8 q0, q1;
  {
    const _Float16* qp = q16 + ((size_t)b * S_ + rid) * 64 + 8 * qd;
    q0 = *(const f16x8*)qp;
    q1 = *(const f16x8*)(qp + 32);
  }

  const int r = tid >> 2, qu = tid & 3;
  {
    const int tokA = st[row0 + r];
    const int tokB = st[row1 + r];
    const f16x8* ska = (const f16x8*)(kn16 + ((size_t)b * S_ + tokA) * 64 + qu * 16);
    const f16x8* skb = (const f16x8*)(kn16 + ((size_t)b * S_ + tokB) * 64 + qu * 16);
    *(f16x8*)(smem + r * 72 + qu * 16)            = ska[0];
    *(f16x8*)(smem + r * 72 + qu * 16 + 8)        = ska[1];
    *(f16x8*)(smem + (64 + r) * 72 + qu * 16)     = skb[0];
    *(f16x8*)(smem + (64 + r) * 72 + qu * 16 + 8) = skb[1];
  }
  __syncthreads();                            // b0

  f32x4 acc[8];
#pragma unroll
  for (int jt = 0; jt < 8; ++jt) acc[jt] = (f32x4){0.f, 0.f, 0.f, 0.f};

  __builtin_amdgcn_s_setprio(1);
#pragma unroll
  for (int jt = 0; jt < 8; ++jt) {
    const _Float16* krow = smem + (16 * jt + m16) * 72;
    const f16x8 kb0 = *(const f16x8*)(krow + 8 * qd);
    const f16x8 kb1 = *(const f16x8*)(krow + 32 + 8 * qd);
    acc[jt] = MFMA16(kb0, q0, acc[jt]);
    acc[jt] = MFMA16(kb1, q1, acc[jt]);
  }
  __builtin_amdgcn_s_setprio(0);

  float m = -1e30f;
#pragma unroll
  for (int jt = 0; jt < 8; ++jt) {
    const int4 cid = *(const int4*)(sIds + 16 * jt + 4 * qd);
    float x;
    x = acc[jt][0]; if (cid.x == rid) x = -5e4f; acc[jt][0] = x; m = fmaxf(m, x);
    x = acc[jt][1]; if (cid.y == rid) x = -5e4f; acc[jt][1] = x; m = fmaxf(m, x);
    x = acc[jt][2]; if (cid.z == rid) x = -5e4f; acc[jt][2] = x; m = fmaxf(m, x);
    x = acc[jt][3]; if (cid.w == rid) x = -5e4f; acc[jt][3] = x; m = fmaxf(m, x);
  }
  m = fmaxf(m, __shfl_xor(m, 16));
  m = fmaxf(m, __shfl_xor(m, 32));
  float sum = 0.f;
#pragma unroll
  for (int jt = 0; jt < 8; ++jt)
#pragma unroll
    for (int rg = 0; rg < 4; ++rg) {
      const float e = __expf(acc[jt][rg] - m);
      acc[jt][rg] = e;
      sum += e;
    }
  sum += __shfl_xor(sum, 16);
  sum += __shfl_xor(sum, 32);
  const float rinv = 1.f / sum;

  const int hh = c >> 7;
  const size_t hb = ((size_t)(b * 8 + hh)) * S_;
  if (qd == 0)
    __builtin_nontemporal_store(m + __logf(sum), &slog[hb + rid]);

  f16x8 pa[4];
#pragma unroll
  for (int s = 0; s < 4; ++s)
#pragma unroll
    for (int j = 0; j < 8; ++j)
      pa[s][j] = (_Float16)acc[2 * s + (j >> 2)][j & 3];

  const int c0 = 2 * r;
  const int k0 = 32 * (c0 >> 5) + 16 * ((c0 >> 2) & 1) + 4 * ((c0 >> 3) & 3) + (c0 & 3);
  const int tok0 = sIds[k0], tok1 = sIds[k0 + 1];
  f16x8 va[2], vb[2];
  {
    const f16x8* s0 = (const f16x8*)(v16 + ((size_t)b * S_ + tok0) * 64 + qu * 16);
    const f16x8* s1 = (const f16x8*)(v16 + ((size_t)b * S_ + tok1) * 64 + qu * 16);
    va[0] = s0[0]; va[1] = s0[1];
    vb[0] = s1[0]; vb[1] = s1[1];
  }
  __syncthreads();                            // b1: all sK reads done

  {
    const int swz = (qu << 3) ^ ((qu & 1) << 5);
    _Float16* dst = smem + (c0 ^ swz);
#pragma unroll
    for (int jj = 0; jj < 16; ++jj) {
      const int d = 16 * qu + jj;
      f16x2 pk; pk[0] = va[jj >> 3][jj & 7]; pk[1] = vb[jj >> 3][jj & 7];
      *(f16x2*)(dst + d * 136) = pk;
    }
  }
  __syncthreads();                            // b2

  f32x4 oacc[4];
#pragma unroll
  for (int dt = 0; dt < 4; ++dt) oacc[dt] = (f32x4){0.f, 0.f, 0.f, 0.f};
  __builtin_amdgcn_s_setprio(1);
#pragma unroll
  for (int s = 0; s < 4; ++s) {
#pragma unroll
    for (int dt = 0; dt < 4; ++dt) {
      const _Float16* vp = smem + (16 * dt + m16) * 136
                         + 32 * (s ^ (dt & 1)) + 8 * (qd ^ dt);
      const f16x8 bv = *(const f16x8*)(vp);
      oacc[dt] = MFMA16(pa[s], bv, oacc[dt]);
    }
  }
  __builtin_amdgcn_s_setprio(0);

  float rin[4];
#pragma unroll
  for (int rg = 0; rg < 4; ++rg) rin[rg] = __shfl(rinv, 4 * qd + rg);

  __syncthreads();                            // b3: all sV reads done
#pragma unroll
  for (int dt = 0; dt < 4; ++dt)
#pragma unroll
    for (int rg = 0; rg < 4; ++rg)
      smem[(16 * w + 4 * qd + rg) * 72 + 16 * dt + m16] =
          (_Float16)(oacc[dt][rg] * rin[rg]);
  __syncthreads();                            // b4

  {
    const int tok = sIds[r];
    const f16x8* srcp = (const f16x8*)(smem + r * 72 + qu * 16);
    const f16x8 o0 = srcp[0], o1 = srcp[1];
    f16x8* dstp = (f16x8*)(so + (hb + tok) * 64 + qu * 16);
    __builtin_nontemporal_store(o0, dstp);
    __builtin_nontemporal_store(o1, dstp + 1);
  }
}

// ---------------------------------------------------------------------------
// Kernel 4: combine rounds — one d-octet per thread, f16x8 loads, float4 x2
// stores (r5 version).
// ---------------------------------------------------------------------------
__global__ __launch_bounds__(256) void combine_kernel(
    const _Float16* __restrict__ so, const float* __restrict__ slog,
    float* __restrict__ out)
{
  const int gid = blockIdx.x * 256 + threadIdx.x;
  const int gt  = gid >> 3;                   // global token b*S + t
  const int oct = gid & 7;                    // d-octet
  const int b   = gt >> 13;
  const int t   = gt & (S_ - 1);
  const size_t base8 = (size_t)(b * 8) * S_ + t;

  float l[8];
#pragma unroll
  for (int h = 0; h < 8; ++h) l[h] = slog[base8 + (size_t)h * S_];
  float m = l[0];
#pragma unroll
  for (int h = 1; h < 8; ++h) m = fmaxf(m, l[h]);
  float wv[8], W = 0.f;
#pragma unroll
  for (int h = 0; h < 8; ++h) { wv[h] = expf(l[h] - m); W += wv[h]; }
  const float iW = 1.f / W;

  float acc[8] = {0.f, 0.f, 0.f, 0.f, 0.f, 0.f, 0.f, 0.f};
#pragma unroll
  for (int h = 0; h < 8; ++h) {
    const f16x8 vv = *(const f16x8*)(so + (base8 + (size_t)h * S_) * 64 + oct * 8);
#pragma unroll
    for (int j = 0; j < 8; ++j) acc[j] = fmaf(wv[h], (float)vv[j], acc[j]);
  }
  float4 o0, o1;
  o0.x = acc[0] * iW; o0.y = acc[1] * iW; o0.z = acc[2] * iW; o0.w = acc[3] * iW;
  o1.x = acc[4] * iW; o1.y = acc[5] * iW; o1.z = acc[6] * iW; o1.w = acc[7] * iW;
  float4* dst = (float4*)(out + (size_t)gt * 64 + oct * 8);
  dst[0] = o0; dst[1] = o1;
}

// ---------------------------------------------------------------------------
extern "C" void kernel_launch(void* const* d_in, const int* in_sizes, int n_in,
                              void* d_out, int out_size, void* d_ws, size_t ws_size,
                              hipStream_t stream)
{
  const float* qk  = (const float*)d_in[0];
  const float* v   = (const float*)d_in[1];
  const float* rot = (const float*)d_in[2];
  float* out = (float*)d_out;

  char* ws = (char*)d_ws;
  const size_t MB = 1ull << 20, KB = 1024;
  int*      bucket = (int*)      (ws + 0 * MB);   // 2 MB
  int*      st     = (int*)      (ws + 2 * MB);   // 2 MB
  float*    slog   = (float*)    (ws + 4 * MB);   // 2 MB
  _Float16* q16    = (_Float16*) (ws + 8 * MB);   // 8 MB
  _Float16* kn16   = (_Float16*) (ws + 16 * MB);  // 8 MB
  _Float16* v16    = (_Float16*) (ws + 24 * MB);  // 8 MB
  _Float16* rotHi  = (_Float16*) (ws + 32 * MB);            // 64 KB
  _Float16* rotLo  = (_Float16*) (ws + 32 * MB + 64 * KB);  // 64 KB
  int*      cnt    = (int*)      (ws + 32 * MB + 128 * KB);
  int2*     list   = (int2*)     (ws + 32 * MB + 192 * KB); // 512 KB
  float*    rotT   = (float*)    (ws + 32 * MB + 768 * KB); // 128 KB
  _Float16* so     = (_Float16*) (ws + 33 * MB);  // 64 MB -> ends at 97 MB
  if (ws_size < 98 * MB) return;

  hipLaunchKernelGGL(rot_prep_kernel, dim3(8),         dim3(256),  0, stream,
                     rot, rotHi, rotLo, rotT, cnt);
  hipLaunchKernelGGL(hash_kernel,     dim3(8 * 128),   dim3(256),  0, stream,
                     qk, v, rotHi, rotLo, q16, kn16, v16, bucket, cnt, list);
  hipLaunchKernelGGL(repair_kernel,   dim3(256),       dim3(256),  0, stream,
                     qk, rotT, cnt, list, bucket);
  hipLaunchKernelGGL(sort_kernel,     dim3(64),        dim3(1024), 0, stream,
                     bucket, st);
  hipLaunchKernelGGL(attn_kernel,     dim3(B_ * NC_),  dim3(256),  0, stream,
                     q16, kn16, v16, st, so, slog);
  hipLaunchKernelGGL(combine_kernel,  dim3(B_ * S_ * 8 / 256), dim3(256), 0, stream,
                     so, slog, out);
}

// Round 8
// 177.582 us; speedup vs baseline: 1.1222x; 1.1222x over previous
//
#include <hip/hip_runtime.h>
#include <math.h>

#define B_  8
#define S_  8192
#define D_  64
#define H_  8
#define NB_ 128
#define NC_ 1024
#define REP_CAP 65536
#define T2_ 2e-3f   // repair margin >= 10x the split-f16 worst-case error (~1.5e-4)

typedef _Float16 f16x8 __attribute__((ext_vector_type(8)));
typedef _Float16 f16x2 __attribute__((ext_vector_type(2)));
typedef float    f32x4 __attribute__((ext_vector_type(4)));
typedef unsigned int uint_;

#define MFMA16(A, Bv, C) __builtin_amdgcn_mfma_f32_16x16x32_f16(A, Bv, C, 0, 0, 0)

// ---------------------------------------------------------------------------
// Kernel 0: rot prep — transpose+split rot into [h][i][f] f16 hi/lo, PLUS
// fp32 rotT [h][i][f] (contiguous per-lane rows for repair); zero cnt.
// ---------------------------------------------------------------------------
__global__ __launch_bounds__(256) void rot_prep_kernel(
    const float* __restrict__ rot, _Float16* __restrict__ rotHi,
    _Float16* __restrict__ rotLo, float* __restrict__ rotT,
    int* __restrict__ cnt)
{
  __shared__ float rs[64 * 64];               // [f][i]
  const int tid = threadIdx.x, h = blockIdx.x;
  if (h == 0 && tid == 0) *cnt = 0;
#pragma unroll
  for (int it = 0; it < 16; ++it) {
    const int f = it * 4 + (tid >> 6), i = tid & 63;
    rs[f * 64 + i] = rot[f * 512 + h * 64 + i];
  }
  __syncthreads();
  const int i = tid & 63, grp = tid >> 6;
  _Float16 hi[16], lo[16];
  float tf[16];
#pragma unroll
  for (int ff = 0; ff < 16; ++ff) {
    const float x = rs[(grp * 16 + ff) * 64 + i];
    tf[ff] = x;
    hi[ff] = (_Float16)x;
    lo[ff] = (_Float16)(x - (float)hi[ff]);
  }
  f16x8* dH = (f16x8*)(rotHi + h * 4096 + i * 64 + grp * 16);
  f16x8* dL = (f16x8*)(rotLo + h * 4096 + i * 64 + grp * 16);
  dH[0] = ((f16x8*)hi)[0]; dH[1] = ((f16x8*)hi)[1];
  dL[0] = ((f16x8*)lo)[0]; dL[1] = ((f16x8*)lo)[1];
  float4* dT = (float4*)(rotT + h * 4096 + i * 64 + grp * 16);
#pragma unroll
  for (int k = 0; k < 4; ++k) dT[k] = ((float4*)tf)[k];
}

// ---------------------------------------------------------------------------
// Kernel 1 (FUSED): token prep (q16/kn16/v16) + hash. b = blockIdx&7 (XCD
// swizzle), rot slices register-prefetched. NEW: qk read from global ONCE —
// prep parks the fp32 tile in LDS rs[64][68]; hash B-frags rebuilt from LDS
// (bit-identical values, fp32 round-trip is exact).
// ---------------------------------------------------------------------------
__global__ __launch_bounds__(256) void hash_kernel(
    const float* __restrict__ qk, const float* __restrict__ v,
    const _Float16* __restrict__ rotHi, const _Float16* __restrict__ rotLo,
    _Float16* __restrict__ q16, _Float16* __restrict__ kn16,
    _Float16* __restrict__ v16,
    int* __restrict__ bucket, int* __restrict__ cnt, int2* __restrict__ list)
{
  __shared__ float rs[64 * 68];               // 17408 B fp32 qk tile
  __shared__ _Float16 rH[64 * 72];            // 9216 B
  __shared__ _Float16 rL[64 * 72];            // 9216 B
  const int tid  = threadIdx.x;
  const int b    = blockIdx.x & 7;            // XCD-batch swizzle
  const int tile = blockIdx.x >> 3;           // 128 tiles x 64 tokens
  const int lane = tid & 63, w = tid >> 6;
  const int m16  = lane & 15, qd = lane >> 4;

  // ---- prep-token part: thread (r, qu) owns quarter-row of token r ----
  {
    const int r = tid >> 2, qu = tid & 3;
    const int gt = b * S_ + tile * 64 + r;
    const size_t off = (size_t)gt * 64 + qu * 16;
    float x[16];
#pragma unroll
    for (int k = 0; k < 4; ++k) ((float4*)x)[k] = ((const float4*)(qk + off))[k];
    // park fp32 tile in LDS for the hash B-fragments
#pragma unroll
    for (int k = 0; k < 4; ++k)
      *(float4*)(rs + r * 68 + qu * 16 + k * 4) = ((float4*)x)[k];
    float ss = 0.f;
#pragma unroll
    for (int k = 0; k < 16; ++k) ss = fmaf(x[k], x[k], ss);
    ss += __shfl_xor(ss, 1); ss += __shfl_xor(ss, 2);
    const float inv = 0.125f / (sqrtf(ss) + 1e-6f);
    f16x8 qh[2], kn[2];
#pragma unroll
    for (int j = 0; j < 16; ++j) {
      qh[j >> 3][j & 7] = (_Float16)x[j];
      kn[j >> 3][j & 7] = (_Float16)(x[j] * inv);
    }
    ((f16x8*)(q16  + off))[0] = qh[0]; ((f16x8*)(q16  + off))[1] = qh[1];
    ((f16x8*)(kn16 + off))[0] = kn[0]; ((f16x8*)(kn16 + off))[1] = kn[1];
    float y[16];
#pragma unroll
    for (int k = 0; k < 4; ++k) ((float4*)y)[k] = ((const float4*)(v + off))[k];
    f16x8 vv[2];
#pragma unroll
    for (int j = 0; j < 16; ++j) vv[j >> 3][j & 7] = (_Float16)y[j];
    ((f16x8*)(v16 + off))[0] = vv[0]; ((f16x8*)(v16 + off))[1] = vv[1];
  }
  __syncthreads();                            // rs tile complete

  // ---- hash part: thread (w, m16, qd) owns token t, dims 8qd.. ----
  const int t = tile * 64 + w * 16 + m16;
  f16x8 BH0, BH1, BL0, BL1;                   // split-f16 B-fragments
  {
    const float* srcl = rs + (w * 16 + m16) * 68 + 8 * qd;
    float x[16];
    ((float4*)x)[0] = *(const float4*)(srcl);
    ((float4*)x)[1] = *(const float4*)(srcl + 4);
    ((float4*)x)[2] = *(const float4*)(srcl + 32);
    ((float4*)x)[3] = *(const float4*)(srcl + 36);
#pragma unroll
    for (int j = 0; j < 8; ++j) {
      const _Float16 h0 = (_Float16)x[j];
      BH0[j] = h0; BL0[j] = (_Float16)(x[j] - (float)h0);
      const _Float16 h1 = (_Float16)x[j + 8];
      BH1[j] = h1; BL1[j] = (_Float16)(x[j + 8] - (float)h1);
    }
  }
  const int srow = tid >> 2, scol = (tid & 3) * 16;
  const uint_ qd16 = (uint_)(qd << 4);

  // prefetch h=0 rot slice into registers
  f16x8 cH0, cH1, cL0, cL1;
  {
    const _Float16* gH = rotHi + srow * 64 + scol;
    const _Float16* gL = rotLo + srow * 64 + scol;
    cH0 = ((const f16x8*)gH)[0]; cH1 = ((const f16x8*)gH)[1];
    cL0 = ((const f16x8*)gL)[0]; cL1 = ((const f16x8*)gL)[1];
  }

#pragma unroll 1
  for (int h = 0; h < 8; ++h) {
    __syncthreads();                          // prev iter's LDS reads done
    f16x8 nH0, nH1, nL0, nL1;
    if (h < 7) {                              // issue h+1 loads (overlap compute)
      const _Float16* gH = rotHi + (h + 1) * 4096 + srow * 64 + scol;
      const _Float16* gL = rotLo + (h + 1) * 4096 + srow * 64 + scol;
      nH0 = ((const f16x8*)gH)[0]; nH1 = ((const f16x8*)gH)[1];
      nL0 = ((const f16x8*)gL)[0]; nL1 = ((const f16x8*)gL)[1];
    }
    *(f16x8*)(rH + srow * 72 + scol)     = cH0;
    *(f16x8*)(rH + srow * 72 + scol + 8) = cH1;
    *(f16x8*)(rL + srow * 72 + scol)     = cL0;
    *(f16x8*)(rL + srow * 72 + scol + 8) = cL1;
    __syncthreads();

    f32x4 acc[4];
#pragma unroll
    for (int mt = 0; mt < 4; ++mt) acc[mt] = (f32x4){0.f, 0.f, 0.f, 0.f};
#pragma unroll
    for (int mt = 0; mt < 4; ++mt) {
      const _Float16* aH = rH + (16 * mt + m16) * 72 + 8 * qd;
      const _Float16* aL = rL + (16 * mt + m16) * 72 + 8 * qd;
      const f16x8 AH0 = *(const f16x8*)aH;
      const f16x8 AH1 = *(const f16x8*)(aH + 32);
      const f16x8 AL0 = *(const f16x8*)aL;
      const f16x8 AL1 = *(const f16x8*)(aL + 32);
      acc[mt] = MFMA16(AH0, BH0, acc[mt]);
      acc[mt] = MFMA16(AH1, BH1, acc[mt]);
      acc[mt] = MFMA16(AH0, BL0, acc[mt]);
      acc[mt] = MFMA16(AH1, BL1, acc[mt]);
      acc[mt] = MFMA16(AL0, BH0, acc[mt]);
      acc[mt] = MFMA16(AL1, BH1, acc[mt]);
    }

    float v1M = -1e30f, v2M = -1e30f, v1m = 1e30f, v2m = 1e30f;
#pragma unroll
    for (int mt = 0; mt < 4; ++mt)
#pragma unroll
      for (int rg = 0; rg < 4; ++rg) {
        uint_ u = __float_as_uint(acc[mt][rg]);
        u = (u & 0xFFFFFFC0u) | qd16 | (uint_)((mt << 2) | rg);
        const float xk = __uint_as_float(u);
        v2M = __builtin_amdgcn_fmed3f(v1M, v2M, xk);
        v1M = fmaxf(v1M, xk);
        v2m = __builtin_amdgcn_fmed3f(v1m, v2m, xk);
        v1m = fminf(v1m, xk);
      }
#pragma unroll
    for (int off = 16; off <= 32; off <<= 1) {
      const float o1M = __shfl_xor(v1M, off), o2M = __shfl_xor(v2M, off);
      v2M = __builtin_amdgcn_fmed3f(v1M, o1M, fmaxf(v2M, o2M));
      v1M = fmaxf(v1M, o1M);
      const float o1m = __shfl_xor(v1m, off), o2m = __shfl_xor(v2m, off);
      v2m = __builtin_amdgcn_fmed3f(v1m, o1m, fminf(v2m, o2m));
      v1m = fminf(v1m, o1m);
    }
    if (qd == 0) {
      const uint_ cM = __float_as_uint(v1M) & 63u;
      const uint_ cm = __float_as_uint(v1m) & 63u;
      const int ixM = 16 * (int)((cM >> 2) & 3u) + 4 * (int)(cM >> 4) + (int)(cM & 3u);
      const int ixm = 16 * (int)((cm >> 2) & 3u) + 4 * (int)(cm >> 4) + (int)(cm & 3u);
      const int bkt = (v1M >= -v1m) ? ixM : 64 + ixm;
      bucket[((size_t)(b * 8 + h)) * S_ + t] = bkt;
      const bool flag = ((v1M - v2M) < T2_) | ((v2m - v1m) < T2_) |
                        (fabsf(v1M + v1m) < T2_);
      if (flag) {
        const int s = atomicAdd(cnt, 1);
        if (s < REP_CAP) list[s] = make_int2(b * 8 + h, t);
      }
    }
    cH0 = nH0; cH1 = nH1; cL0 = nL0; cL1 = nL1;
  }
}

// ---------------------------------------------------------------------------
// Kernel 1b: exact fp64 repair for flagged tokens (rotT contiguous rows).
// ---------------------------------------------------------------------------
__global__ __launch_bounds__(256) void repair_kernel(
    const float* __restrict__ qk, const float* __restrict__ rotT,
    const int* __restrict__ cnt, const int2* __restrict__ list,
    int* __restrict__ bucket)
{
  const int n = min(*cnt, REP_CAP);
  const int lane = threadIdx.x & 63;
  const int wid  = (blockIdx.x * 256 + threadIdx.x) >> 6;
  const int nw   = gridDim.x * 4;
  for (int idx = wid; idx < n; idx += nw) {
    const int bh = list[idx].x, t = list[idx].y;
    const int b = bh >> 3, hh = bh & 7;
    const float* qrow = qk + ((size_t)b * S_ + t) * D_;
    const float* rcol = rotT + hh * 4096 + lane * 64;
    double acc = 0.0;
#pragma unroll
    for (int f0 = 0; f0 < 64; f0 += 4) {
      const float4 rq = *(const float4*)(qrow + f0);
      const float4 rc = *(const float4*)(rcol + f0);
      acc = fma((double)rq.x, (double)rc.x, acc);
      acc = fma((double)rq.y, (double)rc.y, acc);
      acc = fma((double)rq.z, (double)rc.z, acc);
      acc = fma((double)rq.w, (double)rc.w, acc);
    }
    double vM = acc; int iM = lane;
    double vm = acc; int im = lane;
#pragma unroll
    for (int off = 32; off >= 1; off >>= 1) {
      const double voM = __shfl_xor(vM, off); const int ioM = __shfl_xor(iM, off);
      if (voM > vM || (voM == vM && ioM < iM)) { vM = voM; iM = ioM; }
      const double vom = __shfl_xor(vm, off); const int iom = __shfl_xor(im, off);
      if (vom < vm || (vom == vm && iom < im)) { vm = vom; im = iom; }
    }
    if (lane == 0) {
      const int bkt = (vM >= -vm) ? iM : 64 + im;
      bucket[(size_t)bh * S_ + t] = bkt;
    }
  }
}

// ---------------------------------------------------------------------------
// Kernel 2: stable counting sort — ATOMIC-FREE (r5 version). One ballot pass
// computes (bucket, rank, leader counts); 2-wave scan; in-place counts->
// bases; scatter reuses saved ranks. Bit-identical output.
// ---------------------------------------------------------------------------
__global__ __launch_bounds__(1024) void sort_kernel(
    const int* __restrict__ bucket, int* __restrict__ st)
{
  __shared__ uint_ hist32[128 * 67];          // 34304 B; u16 view [bk][134]
  __shared__ unsigned short lb[S_];
  __shared__ int off[128];
  __shared__ int wtot;
  unsigned short* hist16 = (unsigned short*)hist32;
  const int tid = threadIdx.x;
  const int bh  = blockIdx.x;
  const size_t base = (size_t)bh * S_;
  const int lane = tid & 63;
  const unsigned long long ltmask = (1ull << lane) - 1ull;

#pragma unroll
  for (int k = 0; k < 9; ++k) {
    const int i = k * 1024 + tid;
    if (i < 128 * 67) hist32[i] = 0;
  }
  __syncthreads();

  // ---- single ballot pass: labels, ranks, leader counts ----
  int rl[8];
#pragma unroll
  for (int k = 0; k < 8; ++k) {
    const int t = k * 1024 + tid;
    const int bk = bucket[base + t];
    lb[t] = (unsigned short)bk;
    unsigned long long same = ~0ull;
#pragma unroll
    for (int bit = 0; bit < 7; ++bit) {
      const unsigned long long m = __ballot((bk >> bit) & 1);
      same &= ((bk >> bit) & 1) ? m : ~m;
    }
    rl[k] = __popcll(same & ltmask);
    if ((same & ltmask) == 0ull)              // leader of this bucket-set
      hist16[bk * 134 + (t >> 6)] = (unsigned short)__popcll(same);
  }
  __syncthreads();

  // ---- per-bucket totals + 2-wave exclusive scan over 128 buckets ----
  int s = 0;
  if (tid < 128) {
    const uint_* row = hist32 + tid * 67;
#pragma unroll
    for (int g2 = 0; g2 < 64; ++g2) {
      const uint_ wv = row[g2];
      s += (int)((wv & 0xFFFFu) + (wv >> 16));
    }
  }
  int x = s;
#pragma unroll
  for (int d = 1; d < 64; d <<= 1) {
    const int y = __shfl_up(x, d);
    if (lane >= d) x += y;
  }
  if (tid == 63) wtot = x;
  __syncthreads();
  if (tid < 128) {
    if (tid >= 64) x += wtot;
    off[tid] = x - s;                         // exclusive prefix
  }
  __syncthreads();

  // ---- counts -> group bases (in place) ----
  if (tid < 128) {
    int run = off[tid];
    unsigned short* rowp = hist16 + tid * 134;
#pragma unroll
    for (int g = 0; g < 128; ++g) {
      const int cg = rowp[g];
      rowp[g] = (unsigned short)run;
      run += cg;
    }
  }
  __syncthreads();

  // ---- scatter ----
  const int b = bh >> 3, h = bh & 7;
  const size_t stb = (size_t)b * (H_ * S_) + (size_t)h * S_;
#pragma unroll
  for (int k = 0; k < 8; ++k) {
    const int t = k * 1024 + tid;
    const int bk = (int)lb[t];
    const int gb = (int)hist16[bk * 134 + (t >> 6)];
    st[stb + gb + rl[k]] = t;
  }
}

// ---------------------------------------------------------------------------
// Kernel 3: bucketed attention (r5 version — normal write-back stores).
// Swapped QK^T, XCD-batch swizzle, setprio, LDS O-restage epilogue.
// ---------------------------------------------------------------------------
__global__ __launch_bounds__(256, 8) void attn_kernel(
    const _Float16* __restrict__ q16, const _Float16* __restrict__ kn16,
    const _Float16* __restrict__ v16, const int* __restrict__ st,
    _Float16* __restrict__ so, float* __restrict__ slog)
{
  __shared__ _Float16 smem[128 * 72];         // union: sK[128*72] | sV[64*136] | O[64*72]
  __shared__ __align__(16) int sIds[128];

  const int tid = threadIdx.x;
  const int b   = blockIdx.x & 7;             // XCD-batch swizzle
  const int c   = blockIdx.x >> 3;
  const int cm1 = (c + NC_ - 1) & (NC_ - 1);
  const size_t bst = (size_t)b * (H_ * S_);
  const size_t row0 = bst + (size_t)c * 64;
  const size_t row1 = bst + (size_t)cm1 * 64;

  const int lane = tid & 63;
  const int w    = tid >> 6;
  const int m16  = lane & 15;
  const int qd   = lane >> 4;

  if (tid < 128) sIds[tid] = (tid < 64) ? st[row0 + tid] : st[row1 + tid - 64];

  const int rid = st[row0 + 16 * w + m16];
  f16x8 q0, q1;
  {
    const _Float16* qp = q16 + ((size_t)b * S_ + rid) * 64 + 8 * qd;
    q0 = *(const f16x8*)qp;
    q1 = *(const f16x8*)(qp + 32);
  }

  const int r = tid >> 2, qu = tid & 3;
  {
    const int tokA = st[row0 + r];
    const int tokB = st[row1 + r];
    const f16x8* ska = (const f16x8*)(kn16 + ((size_t)b * S_ + tokA) * 64 + qu * 16);
    const f16x8* skb = (const f16x8*)(kn16 + ((size_t)b * S_ + tokB) * 64 + qu * 16);
    *(f16x8*)(smem + r * 72 + qu * 16)            = ska[0];
    *(f16x8*)(smem + r * 72 + qu * 16 + 8)        = ska[1];
    *(f16x8*)(smem + (64 + r) * 72 + qu * 16)     = skb[0];
    *(f16x8*)(smem + (64 + r) * 72 + qu * 16 + 8) = skb[1];
  }
  __syncthreads();                            // b0

  f32x4 acc[8];
#pragma unroll
  for (int jt = 0; jt < 8; ++jt) acc[jt] = (f32x4){0.f, 0.f, 0.f, 0.f};

  __builtin_amdgcn_s_setprio(1);
#pragma unroll
  for (int jt = 0; jt < 8; ++jt) {
    const _Float16* krow = smem + (16 * jt + m16) * 72;
    const f16x8 kb0 = *(const f16x8*)(krow + 8 * qd);
    const f16x8 kb1 = *(const f16x8*)(krow + 32 + 8 * qd);
    acc[jt] = MFMA16(kb0, q0, acc[jt]);
    acc[jt] = MFMA16(kb1, q1, acc[jt]);
  }
  __builtin_amdgcn_s_setprio(0);

  float m = -1e30f;
#pragma unroll
  for (int jt = 0; jt < 8; ++jt) {
    const int4 cid = *(const int4*)(sIds + 16 * jt + 4 * qd);
    float x;
    x = acc[jt][0]; if (cid.x == rid) x = -5e4f; acc[jt][0] = x; m = fmaxf(m, x);
    x = acc[jt][1]; if (cid.y == rid) x = -5e4f; acc[jt][1] = x; m = fmaxf(m, x);
    x = acc[jt][2]; if (cid.z == rid) x = -5e4f; acc[jt][2] = x; m = fmaxf(m, x);
    x = acc[jt][3]; if (cid.w == rid) x = -5e4f; acc[jt][3] = x; m = fmaxf(m, x);
  }
  m = fmaxf(m, __shfl_xor(m, 16));
  m = fmaxf(m, __shfl_xor(m, 32));
  float sum = 0.f;
#pragma unroll
  for (int jt = 0; jt < 8; ++jt)
#pragma unroll
    for (int rg = 0; rg < 4; ++rg) {
      const float e = __expf(acc[jt][rg] - m);
      acc[jt][rg] = e;
      sum += e;
    }
  sum += __shfl_xor(sum, 16);
  sum += __shfl_xor(sum, 32);
  const float rinv = 1.f / sum;

  const int hh = c >> 7;
  const size_t hb = ((size_t)(b * 8 + hh)) * S_;
  if (qd == 0) slog[hb + rid] = m + __logf(sum);

  f16x8 pa[4];
#pragma unroll
  for (int s = 0; s < 4; ++s)
#pragma unroll
    for (int j = 0; j < 8; ++j)
      pa[s][j] = (_Float16)acc[2 * s + (j >> 2)][j & 3];

  const int c0 = 2 * r;
  const int k0 = 32 * (c0 >> 5) + 16 * ((c0 >> 2) & 1) + 4 * ((c0 >> 3) & 3) + (c0 & 3);
  const int tok0 = sIds[k0], tok1 = sIds[k0 + 1];
  f16x8 va[2], vb[2];
  {
    const f16x8* s0 = (const f16x8*)(v16 + ((size_t)b * S_ + tok0) * 64 + qu * 16);
    const f16x8* s1 = (const f16x8*)(v16 + ((size_t)b * S_ + tok1) * 64 + qu * 16);
    va[0] = s0[0]; va[1] = s0[1];
    vb[0] = s1[0]; vb[1] = s1[1];
  }
  __syncthreads();                            // b1: all sK reads done

  {
    const int swz = (qu << 3) ^ ((qu & 1) << 5);
    _Float16* dst = smem + (c0 ^ swz);
#pragma unroll
    for (int jj = 0; jj < 16; ++jj) {
      const int d = 16 * qu + jj;
      f16x2 pk; pk[0] = va[jj >> 3][jj & 7]; pk[1] = vb[jj >> 3][jj & 7];
      *(f16x2*)(dst + d * 136) = pk;
    }
  }
  __syncthreads();                            // b2

  f32x4 oacc[4];
#pragma unroll
  for (int dt = 0; dt < 4; ++dt) oacc[dt] = (f32x4){0.f, 0.f, 0.f, 0.f};
  __builtin_amdgcn_s_setprio(1);
#pragma unroll
  for (int s = 0; s < 4; ++s) {
#pragma unroll
    for (int dt = 0; dt < 4; ++dt) {
      const _Float16* vp = smem + (16 * dt + m16) * 136
                         + 32 * (s ^ (dt & 1)) + 8 * (qd ^ dt);
      const f16x8 bv = *(const f16x8*)(vp);
      oacc[dt] = MFMA16(pa[s], bv, oacc[dt]);
    }
  }
  __builtin_amdgcn_s_setprio(0);

  float rin[4];
#pragma unroll
  for (int rg = 0; rg < 4; ++rg) rin[rg] = __shfl(rinv, 4 * qd + rg);

  __syncthreads();                            // b3: all sV reads done
#pragma unroll
  for (int dt = 0; dt < 4; ++dt)
#pragma unroll
    for (int rg = 0; rg < 4; ++rg)
      smem[(16 * w + 4 * qd + rg) * 72 + 16 * dt + m16] =
          (_Float16)(oacc[dt][rg] * rin[rg]);
  __syncthreads();                            // b4

  {
    const int tok = sIds[r];
    const f16x8* srcp = (const f16x8*)(smem + r * 72 + qu * 16);
    const f16x8 o0 = srcp[0], o1 = srcp[1];
    f16x8* dstp = (f16x8*)(so + (hb + tok) * 64 + qu * 16);
    dstp[0] = o0; dstp[1] = o1;
  }
}

// ---------------------------------------------------------------------------
// Kernel 4: combine rounds — one d-octet per thread, f16x8 loads, float4 x2
// stores. NEW: XCD-matched mapping (b = blk&7) so each block reads so/slog
// lines that are dirty in ITS XCD's L2 (attn wrote batch b on XCD b).
// Arithmetic identical per output element.
// ---------------------------------------------------------------------------
__global__ __launch_bounds__(256) void combine_kernel(
    const _Float16* __restrict__ so, const float* __restrict__ slog,
    float* __restrict__ out)
{
  const int blk = blockIdx.x;                 // 2048
  const int b   = blk & 7;                    // XCD match with attn
  const int t   = (blk >> 3) * 32 + (threadIdx.x >> 3);
  const int oct = threadIdx.x & 7;            // d-octet
  const size_t base8 = (size_t)(b * 8) * S_ + t;

  float l[8];
#pragma unroll
  for (int h = 0; h < 8; ++h) l[h] = slog[base8 + (size_t)h * S_];
  float m = l[0];
#pragma unroll
  for (int h = 1; h < 8; ++h) m = fmaxf(m, l[h]);
  float wv[8], W = 0.f;
#pragma unroll
  for (int h = 0; h < 8; ++h) { wv[h] = expf(l[h] - m); W += wv[h]; }
  const float iW = 1.f / W;

  float acc[8] = {0.f, 0.f, 0.f, 0.f, 0.f, 0.f, 0.f, 0.f};
#pragma unroll
  for (int h = 0; h < 8; ++h) {
    const f16x8 vv = *(const f16x8*)(so + (base8 + (size_t)h * S_) * 64 + oct * 8);
#pragma unroll
    for (int j = 0; j < 8; ++j) acc[j] = fmaf(wv[h], (float)vv[j], acc[j]);
  }
  float4 o0, o1;
  o0.x = acc[0] * iW; o0.y = acc[1] * iW; o0.z = acc[2] * iW; o0.w = acc[3] * iW;
  o1.x = acc[4] * iW; o1.y = acc[5] * iW; o1.z = acc[6] * iW; o1.w = acc[7] * iW;
  float4* dst = (float4*)(out + ((size_t)b * S_ + t) * 64 + oct * 8);
  dst[0] = o0; dst[1] = o1;
}

// ---------------------------------------------------------------------------
extern "C" void kernel_launch(void* const* d_in, const int* in_sizes, int n_in,
                              void* d_out, int out_size, void* d_ws, size_t ws_size,
                              hipStream_t stream)
{
  const float* qk  = (const float*)d_in[0];
  const float* v   = (const float*)d_in[1];
  const float* rot = (const float*)d_in[2];
  float* out = (float*)d_out;

  char* ws = (char*)d_ws;
  const size_t MB = 1ull << 20, KB = 1024;
  int*      bucket = (int*)      (ws + 0 * MB);   // 2 MB
  int*      st     = (int*)      (ws + 2 * MB);   // 2 MB
  float*    slog   = (float*)    (ws + 4 * MB);   // 2 MB
  _Float16* q16    = (_Float16*) (ws + 8 * MB);   // 8 MB
  _Float16* kn16   = (_Float16*) (ws + 16 * MB);  // 8 MB
  _Float16* v16    = (_Float16*) (ws + 24 * MB);  // 8 MB
  _Float16* rotHi  = (_Float16*) (ws + 32 * MB);            // 64 KB
  _Float16* rotLo  = (_Float16*) (ws + 32 * MB + 64 * KB);  // 64 KB
  int*      cnt    = (int*)      (ws + 32 * MB + 128 * KB);
  int2*     list   = (int2*)     (ws + 32 * MB + 192 * KB); // 512 KB
  float*    rotT   = (float*)    (ws + 32 * MB + 768 * KB); // 128 KB
  _Float16* so     = (_Float16*) (ws + 33 * MB);  // 64 MB -> ends at 97 MB
  if (ws_size < 98 * MB) return;

  hipLaunchKernelGGL(rot_prep_kernel, dim3(8),         dim3(256),  0, stream,
                     rot, rotHi, rotLo, rotT, cnt);
  hipLaunchKernelGGL(hash_kernel,     dim3(8 * 128),   dim3(256),  0, stream,
                     qk, v, rotHi, rotLo, q16, kn16, v16, bucket, cnt, list);
  hipLaunchKernelGGL(repair_kernel,   dim3(256),       dim3(256),  0, stream,
                     qk, rotT, cnt, list, bucket);
  hipLaunchKernelGGL(sort_kernel,     dim3(64),        dim3(1024), 0, stream,
                     bucket, st);
  hipLaunchKernelGGL(attn_kernel,     dim3(B_ * NC_),  dim3(256),  0, stream,
                     q16, kn16, v16, st, so, slog);
  hipLaunchKernelGGL(combine_kernel,  dim3(B_ * S_ * 8 / 256), dim3(256), 0, stream,
                     so, slog, out);
}